// Round 12
// baseline (375.010 us; speedup 1.0000x reference)
//
#include <hip/hip_runtime.h>
#include <hip/hip_bf16.h>

#define B_ 4
#define N_ 2048
#define C_ 1024
#define H_ 16
#define D_ 64
#define QSCALE_ 0.1803368801f   /* 0.125 * log2(e): softmax uses exp2 */

typedef _Float16 f16;
typedef __attribute__((ext_vector_type(8))) _Float16 f16x8;
typedef __attribute__((ext_vector_type(4))) _Float16 f16x4;
typedef __attribute__((ext_vector_type(4))) float f32x4;
typedef __attribute__((ext_vector_type(16))) float f32x16;
#define MFMA16(a, b, c) __builtin_amdgcn_mfma_f32_16x16x32_f16(a, b, c, 0, 0, 0)
#define MFMA32(a, b, c) __builtin_amdgcn_mfma_f32_32x32x16_f16(a, b, c, 0, 0, 0)

__device__ inline void gload_lds16(const f16* g, f16* l) {
    __builtin_amdgcn_global_load_lds(
        (const __attribute__((address_space(1))) void*)g,
        (__attribute__((address_space(3))) void*)l, 16, 0, 0);
}

// ---------------- f32 -> f16 convert (x, qkv_w, proj_w) ----------------
#define NX_ 8388608u
#define NW1_ 3145728u
#define NW2_ 1048576u

__global__ __launch_bounds__(256) void convert_kernel(
    const float* __restrict__ x, const float* __restrict__ w1, const float* __restrict__ w2,
    f16* __restrict__ xo, f16* __restrict__ w1o, f16* __restrict__ w2o)
{
    const unsigned q = blockIdx.x * 256 + threadIdx.x;
    const unsigned i = q << 2;
    const float* src;
    f16* dst;
    if (i < NX_)              { src = x  + i;               dst = xo  + i; }
    else if (i < NX_ + NW1_)  { src = w1 + (i - NX_);       dst = w1o + (i - NX_); }
    else                      { src = w2 + (i - NX_ - NW1_); dst = w2o + (i - NX_ - NW1_); }
    const float4 v = *(const float4*)src;
    f16x4 h;
    h[0] = (f16)v.x; h[1] = (f16)v.y; h[2] = (f16)v.z; h[3] = (f16)v.w;
    *(f16x4*)dst = h;
}

// ---------------- f16 MFMA GEMM: C[m][o] = sum_k A[m][k] * W[o][k] ----------------
__global__ __launch_bounds__(256) void qkv_gemm_f16(
    const f16* __restrict__ Xh,        // [8192][1024]
    const f16* __restrict__ Wh,        // [3072][1024]
    const float* __restrict__ qkv_b,
    const float* __restrict__ bias_mask,
    f16* __restrict__ Qh,              // [BH][N][D] (pre-scaled by QSCALE_)
    f16* __restrict__ Kh,              // [BH][N][D]
    f16* __restrict__ Vt)              // [BH][D][N]
{
    __shared__ f16 As[128 * 64];
    __shared__ f16 Bs[128 * 64];
    const int tid  = threadIdx.x;
    const int bm   = blockIdx.x * 128;
    const int bo   = blockIdx.y * 128;
    const int lane = tid & 63, lo = lane & 15, grp = lane >> 4;
    const int wave = tid >> 6, wr = wave >> 1, wc = wave & 1;
    const int sr = tid >> 3, cg = tid & 7;
    const int scol = (cg ^ (sr & 7)) << 3;

    f32x4 acc[4][4];
    #pragma unroll
    for (int m = 0; m < 4; ++m)
        #pragma unroll
        for (int n = 0; n < 4; ++n) acc[m][n] = f32x4{0.f, 0.f, 0.f, 0.f};

    for (int k0 = 0; k0 < 1024; k0 += 64) {
        #pragma unroll
        for (int i = 0; i < 4; ++i) {
            const int tr = i * 32 + sr;
            gload_lds16(Xh + (size_t)(bm + tr) * 1024 + k0 + scol, As + (i * 2048 + tid * 8));
            gload_lds16(Wh + (size_t)(bo + tr) * 1024 + k0 + scol, Bs + (i * 2048 + tid * 8));
        }
        __syncthreads();
        #pragma unroll
        for (int kh = 0; kh < 2; ++kh) {
            f16x8 af[4], bfr[4];
            #pragma unroll
            for (int m = 0; m < 4; ++m) {
                const int row = wr * 64 + m * 16 + lo;
                af[m] = *(const f16x8*)(As + row * 64 + ((((kh << 2) + grp) << 3) ^ ((row & 7) << 3)));
            }
            #pragma unroll
            for (int n = 0; n < 4; ++n) {
                const int row = wc * 64 + n * 16 + lo;
                bfr[n] = *(const f16x8*)(Bs + row * 64 + ((((kh << 2) + grp) << 3) ^ ((row & 7) << 3)));
            }
            #pragma unroll
            for (int m = 0; m < 4; ++m)
                #pragma unroll
                for (int n = 0; n < 4; ++n)
                    acc[m][n] = MFMA16(af[m], bfr[n], acc[m][n]);
        }
        __syncthreads();
    }
    #pragma unroll
    for (int ni = 0; ni < 4; ++ni) {
        const int o = bo + wc * 64 + ni * 16 + lo;
        const float bias = qkv_b[o] * bias_mask[o];
        const int s = o >> 10, h = (o >> 6) & 15, d = o & 63;
        #pragma unroll
        for (int mi = 0; mi < 4; ++mi) {
            #pragma unroll
            for (int r = 0; r < 4; ++r) {
                const int m = bm + wr * 64 + mi * 16 + grp * 4 + r;
                const int b = m >> 11, n = m & (N_ - 1);
                const int bh = b * H_ + h;
                const float val = acc[mi][ni][r] + bias;
                if (s == 0)      Qh[((size_t)bh * N_ + n) * D_ + d] = (f16)(val * QSCALE_);
                else if (s == 1) Kh[((size_t)bh * N_ + n) * D_ + d] = (f16)val;
                else             Vt[((size_t)bh * D_ + d) * N_ + n] = (f16)val;
            }
        }
    }
}

__global__ __launch_bounds__(256) void proj_gemm_f16(
    const f16* __restrict__ Ah,        // [8192][1024] attn out
    const f16* __restrict__ Wh,        // [1024][1024]
    const float* __restrict__ proj_b,
    float* __restrict__ Out)           // [8192][1024] f32
{
    __shared__ f16 As[128 * 64];
    __shared__ f16 Bs[128 * 64];
    const int tid  = threadIdx.x;
    const int bm   = blockIdx.x * 128;
    const int bo   = blockIdx.y * 128;
    const int lane = tid & 63, lo = lane & 15, grp = lane >> 4;
    const int wave = tid >> 6, wr = wave >> 1, wc = wave & 1;
    const int sr = tid >> 3, cg = tid & 7;
    const int scol = (cg ^ (sr & 7)) << 3;

    f32x4 acc[4][4];
    #pragma unroll
    for (int m = 0; m < 4; ++m)
        #pragma unroll
        for (int n = 0; n < 4; ++n) acc[m][n] = f32x4{0.f, 0.f, 0.f, 0.f};

    for (int k0 = 0; k0 < 1024; k0 += 64) {
        #pragma unroll
        for (int i = 0; i < 4; ++i) {
            const int tr = i * 32 + sr;
            gload_lds16(Ah + (size_t)(bm + tr) * 1024 + k0 + scol, As + (i * 2048 + tid * 8));
            gload_lds16(Wh + (size_t)(bo + tr) * 1024 + k0 + scol, Bs + (i * 2048 + tid * 8));
        }
        __syncthreads();
        #pragma unroll
        for (int kh = 0; kh < 2; ++kh) {
            f16x8 af[4], bfr[4];
            #pragma unroll
            for (int m = 0; m < 4; ++m) {
                const int row = wr * 64 + m * 16 + lo;
                af[m] = *(const f16x8*)(As + row * 64 + ((((kh << 2) + grp) << 3) ^ ((row & 7) << 3)));
            }
            #pragma unroll
            for (int n = 0; n < 4; ++n) {
                const int row = wc * 64 + n * 16 + lo;
                bfr[n] = *(const f16x8*)(Bs + row * 64 + ((((kh << 2) + grp) << 3) ^ ((row & 7) << 3)));
            }
            #pragma unroll
            for (int m = 0; m < 4; ++m)
                #pragma unroll
                for (int n = 0; n < 4; ++n)
                    acc[m][n] = MFMA16(af[m], bfr[n], acc[m][n]);
        }
        __syncthreads();
    }
    #pragma unroll
    for (int ni = 0; ni < 4; ++ni) {
        const int o = bo + wc * 64 + ni * 16 + lo;
        const float pb = proj_b[o];
        #pragma unroll
        for (int mi = 0; mi < 4; ++mi) {
            #pragma unroll
            for (int r = 0; r < 4; ++r) {
                const int m = bm + wr * 64 + mi * 16 + grp * 4 + r;
                Out[(size_t)m * C_ + o] = acc[mi][ni][r] + pb;
            }
        }
    }
}

// ---------------- kv-split flash attention (r10 body + defer-rescale + exp2) ----------------
// Grid (N/128, BH*2): blockIdx.y = bh*2 + split; each block does 1024 kv positions.
// Partials: PO[split][bh][n][d] = O/l (f16), ML[split][bh][n] = (m, l) f32.
__global__ __launch_bounds__(256) void attn_fa5_kernel(
    const f16* __restrict__ Qb,  // [BH][N][D] (scaled by QSCALE_)
    const f16* __restrict__ Kb,  // [BH][N][D]
    const f16* __restrict__ Vt,  // [BH][D][N]
    f16* __restrict__ PO,        // [2][BH][N][D]
    float* __restrict__ ML)      // [2][BH][N][2]
{
    __shared__ f16 Plds[4][32 * 36];
    const int tid  = threadIdx.x;
    const int wave = tid >> 6;
    const int lane = tid & 63;
    const int lo   = lane & 31;
    const int hi   = lane >> 5;
    const int bh    = blockIdx.y >> 1;
    const int split = blockIdx.y & 1;
    const int q0   = blockIdx.x * 128 + wave * 32;
    const size_t base = (size_t)bh * (N_ * D_);

    f16x8 qf[4];
    #pragma unroll
    for (int dc = 0; dc < 4; ++dc)
        qf[dc] = *(const f16x8*)(Qb + base + (size_t)(q0 + lo) * D_ + dc * 16 + hi * 8);

    const f32x16 zero16 = {};
    f32x16 o0 = zero16, o1 = zero16;   // O^T: reg r = O[d=(dh*32)+(r&3)+8(r>>2)+4hi][q=lo]
    float m = -1e30f, lsum = 0.f;

    const f16* Kp = Kb + base;
    const f16* Vp = Vt + base;
    f16* pw = &Plds[wave][0];

    const int kv_beg = split << 10;
    for (int kv0 = kv_beg; kv0 < kv_beg + 1024; kv0 += 32) {
        // K A-frags (row=kv=lo, k = d = dc*16 + hi*8 + e)
        const f16* kr = Kp + (size_t)(kv0 + lo) * D_ + hi * 8;
        const f16x8 kf0 = *(const f16x8*)(kr);
        const f16x8 kf1 = *(const f16x8*)(kr + 16);
        const f16x8 kf2 = *(const f16x8*)(kr + 32);
        const f16x8 kf3 = *(const f16x8*)(kr + 48);
        f32x16 s = MFMA32(kf0, qf[0], zero16);
        s = MFMA32(kf1, qf[1], s);
        s = MFMA32(kf2, qf[2], s);
        s = MFMA32(kf3, qf[3], s);

        // V^T A-frags (row=d, k = kv offset hi*8+e)
        const f16x8 vf00 = *(const f16x8*)(Vp + (size_t)(lo) * N_ + kv0 + hi * 8);
        const f16x8 vf01 = *(const f16x8*)(Vp + (size_t)(lo) * N_ + kv0 + 16 + hi * 8);
        const f16x8 vf10 = *(const f16x8*)(Vp + (size_t)(32 + lo) * N_ + kv0 + hi * 8);
        const f16x8 vf11 = *(const f16x8*)(Vp + (size_t)(32 + lo) * N_ + kv0 + 16 + hi * 8);

        // ---- online softmax in exp2 domain (tree reduce + exact defer-rescale)
        float t01 = fmaxf(s[0], s[1]),  t23 = fmaxf(s[2], s[3]);
        float t45 = fmaxf(s[4], s[5]),  t67 = fmaxf(s[6], s[7]);
        float t89 = fmaxf(s[8], s[9]),  tab = fmaxf(s[10], s[11]);
        float tcd = fmaxf(s[12], s[13]), tef = fmaxf(s[14], s[15]);
        float tmax = fmaxf(fmaxf(fmaxf(t01, t23), fmaxf(t45, t67)),
                           fmaxf(fmaxf(t89, tab), fmaxf(tcd, tef)));
        tmax = fmaxf(tmax, __shfl_xor(tmax, 32, 64));
        if (__any(tmax > m)) {
            const float mn = fmaxf(m, tmax);
            const float corr = exp2f(m - mn);
            m = mn; lsum *= corr;
            #pragma unroll
            for (int r = 0; r < 16; ++r) { o0[r] *= corr; o1[r] *= corr; }
        }
        float p[16];
        #pragma unroll
        for (int r = 0; r < 16; ++r) p[r] = exp2f(s[r] - m);
        float rs = (((p[0]+p[1])+(p[2]+p[3])) + ((p[4]+p[5])+(p[6]+p[7])))
                 + (((p[8]+p[9])+(p[10]+p[11])) + ((p[12]+p[13])+(p[14]+p[15])));
        rs += __shfl_xor(rs, 32, 64);
        lsum += rs;

        // ---- P -> LDS (row q=lo; reg pairs are consecutive kv), read PV B-frags
        #pragma unroll
        for (int i = 0; i < 8; ++i) {
            const int kvp = ((i & 1) << 1) + ((i >> 1) << 3) + (hi << 2);
            const f16 h0 = (f16)p[2 * i];
            const f16 h1 = (f16)p[2 * i + 1];
            const unsigned w = (unsigned)__builtin_bit_cast(unsigned short, h0) |
                               ((unsigned)__builtin_bit_cast(unsigned short, h1) << 16);
            *(unsigned*)(pw + lo * 36 + kvp) = w;
        }
        const f16x8 pb1 = *(const f16x8*)(pw + lo * 36 + hi * 8);
        const f16x8 pb2 = *(const f16x8*)(pw + lo * 36 + 16 + hi * 8);

        o0 = MFMA32(vf00, pb1, o0);
        o0 = MFMA32(vf01, pb2, o0);
        o1 = MFMA32(vf10, pb1, o1);
        o1 = MFMA32(vf11, pb2, o1);
    }

    // ---- epilogue: write normalized partial O (f16) + (m, l) f32
    const float inv = 1.f / lsum;
    const size_t prow = ((size_t)split * (B_ * H_) + bh) * N_ + (q0 + lo);
    f16* outp = PO + prow * D_;
    #pragma unroll
    for (int dh = 0; dh < 2; ++dh) {
        #pragma unroll
        for (int j = 0; j < 4; ++j) {
            const int d0 = dh * 32 + 8 * j + 4 * hi;
            f16x4 st;
            #pragma unroll
            for (int e = 0; e < 4; ++e) {
                const float v = (dh == 0 ? o0[4 * j + e] : o1[4 * j + e]) * inv;
                st[e] = (f16)v;
            }
            *(f16x4*)(outp + d0) = st;
        }
    }
    if (hi == 0) {
        ML[2 * prow]     = m;
        ML[2 * prow + 1] = lsum;
    }
}

// ---------------- merge the two kv-split partials (exact, f32 weights) ----------------
__global__ __launch_bounds__(256) void attn_merge_kernel(
    const f16* __restrict__ PO, const float* __restrict__ ML, f16* __restrict__ AO)
{
    const unsigned t = blockIdx.x * 256 + threadIdx.x;   // 1048576 threads
    const unsigned row = t >> 3;                         // bh*N + n
    const int dblk = (int)(t & 7) << 3;
    const int bh = (int)(row >> 11);
    const int n  = (int)(row & 2047);
    const size_t BHN = (size_t)B_ * H_ * N_;
    const float m1 = ML[2 * (size_t)row],        l1 = ML[2 * (size_t)row + 1];
    const float m2 = ML[2 * (BHN + row)],        l2 = ML[2 * (BHN + row) + 1];
    const float mm = fmaxf(m1, m2);
    const float a1 = exp2f(m1 - mm) * l1;
    const float a2 = exp2f(m2 - mm) * l2;
    const float inv = 1.f / (a1 + a2);
    const float w1 = a1 * inv, w2 = a2 * inv;
    const f16x8 p1 = *(const f16x8*)(PO + (size_t)row * D_ + dblk);
    const f16x8 p2 = *(const f16x8*)(PO + (BHN + row) * D_ + dblk);
    const int b = bh >> 4, h = bh & 15;
    f16* outp = AO + ((size_t)(b * N_ + n)) * C_ + h * D_ + dblk;
    f16x8 st;
    #pragma unroll
    for (int e = 0; e < 8; ++e)
        st[e] = (f16)(w1 * (float)p1[e] + w2 * (float)p2[e]);
    *(f16x8*)outp = st;
}

extern "C" void kernel_launch(void* const* d_in, const int* in_sizes, int n_in,
                              void* d_out, int out_size, void* d_ws, size_t ws_size,
                              hipStream_t stream) {
    const float* x         = (const float*)d_in[0];
    const float* qkv_w     = (const float*)d_in[1];
    const float* qkv_b     = (const float*)d_in[2];
    const float* bias_mask = (const float*)d_in[3];
    const float* proj_w    = (const float*)d_in[4];
    const float* proj_b    = (const float*)d_in[5];
    float* out = (float*)d_out;

    const size_t NE = (size_t)B_ * H_ * N_ * D_;   // 8388608
    f16* Xh  = (f16*)d_ws;          // NE
    f16* Wh  = Xh + NE;             // NW1_
    f16* Ph  = Wh + NW1_;           // NW2_
    f16* Qh  = Ph + NW2_;           // NE
    f16* Kh  = Qh + NE;             // NE
    f16* Vt  = Kh + NE;             // NE
    f16* AOh = Vt + NE;             // NE
    f16* PO  = AOh + NE;            // 2*NE
    float* ML = (float*)(PO + 2 * NE);  // 2*BH*N*2 f32 = 2 MB; total ~128 MB

    dim3 blk(256);
    convert_kernel<<<12288, blk, 0, stream>>>(x, qkv_w, proj_w, Xh, Wh, Ph);
    qkv_gemm_f16<<<dim3(64, 24), blk, 0, stream>>>(Xh, Wh, qkv_b, bias_mask, Qh, Kh, Vt);
    attn_fa5_kernel<<<dim3(N_ / 128, B_ * H_ * 2), blk, 0, stream>>>(Qh, Kh, Vt, PO, ML);
    attn_merge_kernel<<<4096, blk, 0, stream>>>(PO, ML, AOh);
    proj_gemm_f16<<<dim3(64, 8), blk, 0, stream>>>(AOh, Ph, proj_b, out);
}